// Round 5
// baseline (1294.442 us; speedup 1.0000x reference)
//
#include <hip/hip_runtime.h>
#include <hip/hip_cooperative_groups.h>
#include <math.h>

namespace cg = cooperative_groups;

#define NN 2048
#define MAX_ITER 1000
#define TOLF 1e-6f
#define TPB 512
#define NBLK 256
#define WPB 8                 // waves per block; NBLK*WPB == NN (one wave per row)
#define NWORD 64              // count words per parity (one per 32 rows)
#define CWSTRIDE 16           // u32 stride between count words (64 B apart)
#define ROWS_PER_WORD (NN / NWORD)   // 32
#define SPIN_LIMIT (1 << 14)
#define LDS_SPIN_LIMIT (1 << 22)
#define GO_ABORT 0x7fffffff

__global__ __launch_bounds__(TPB, 1)
void xgr_sinkhorn(const float* __restrict__ Mm,
                  const float* __restrict__ Gg,
                  const int* __restrict__ eps_p,
                  float* __restrict__ out,
                  unsigned int* __restrict__ ws32)
{
    __shared__ float  m_lds[WPB][NN];   // 64 KB: this block's 8 M rows
    __shared__ float  fA[NN], fB[NN];   // f_t staging, double-buffered by parity
    __shared__ int    s_go;             // latest detected pass (wave0 -> others)
    __shared__ int    s_viol_val;       // viol word for the current decision
    __shared__ double s_part[WPB];

    // ---- workspace (poisoned 0xAA; init below)
    // [0,2048)      cw: 2 parities x 64 count words, stride 16 u32 (monotone)
    // [2048,4096)   fbuf0 (f_t, even t)   [4096,6144) fbuf1 (odd t)
    // [6144,6272)   viol words (one per convergence check)
    // [6272,...)    acc (double), done_cnt, abort flag
    unsigned int* cw    = ws32;
    float*        fbuf0 = (float*)(ws32 + 2048);
    float*        fbuf1 = (float*)(ws32 + 4096);
    unsigned int* viol  = ws32 + 6144;
    double*       acc   = (double*)(ws32 + 6272);
    unsigned int* done_cnt = ws32 + 6276;
    unsigned int* abortp   = ws32 + 6277;

    const int tid  = threadIdx.x;
    const int lane = tid & 63;
    const int wave = tid >> 6;
    const int row  = blockIdx.x * WPB + wave;
    const int gtid = blockIdx.x * TPB + tid;

    if (gtid < 2048) {
        // parity-0 words start "filled" (f_0 = init fill); all else 0
        cw[gtid] = (gtid < 1024 && (gtid & (CWSTRIDE - 1)) == 0) ? (unsigned)ROWS_PER_WORD : 0u;
        fbuf0[gtid] = 0.0f;              // f_0 = 0
    }
    if (gtid < 128) viol[gtid] = 0u;
    if (gtid == 0) { *acc = 0.0; *done_cnt = 0u; *abortp = 0u; }
    if (tid == 0)  { s_go = -1; s_viol_val = 1; }

    const int ebits = *eps_p;
    const float eps = (ebits >= 1 && ebits <= (1 << 20)) ? (float)ebits
                                                         : __int_as_float(ebits);
    const float inv_eps = 1.0f / eps;

    // stage this block's 8 M rows into LDS (once)
    {
        const float4* Mrow = (const float4*)(Mm + (size_t)row * NN);
        float4* ml4 = (float4*)m_lds[wave];
        #pragma unroll
        for (int k = 0; k < 8; ++k) {
            const int idx = (k << 6) + lane;
            ml4[idx] = Mrow[idx];
        }
    }

    cg::this_grid().sync();   // init + LDS visible; count protocol takes over

    float* f_final = nullptr;
    bool   aborted = false;

    for (int t = 0; ; ++t) {
        const int p = t & 1;
        float* fl = p ? fB : fA;
        const float* fsrc = p ? fbuf1 : fbuf0;

        // ---- wave 0 polls the 64 count words (lane w owns word w); others spin on LDS
        if (wave == 0) {
            const unsigned int tgt = (unsigned int)((t / 2 + 1) * ROWS_PER_WORD);
            unsigned int* cwp = &cw[p * 1024 + lane * CWSTRIDE];
            int guard = 0; bool ab = false;
            for (;;) {
                const unsigned int v = __hip_atomic_load(cwp, __ATOMIC_RELAXED, __HIP_MEMORY_SCOPE_AGENT);
                if (__all(v >= tgt)) break;
                if ((++guard & 63) == 0) {
                    if (__hip_atomic_load(abortp, __ATOMIC_RELAXED, __HIP_MEMORY_SCOPE_AGENT)) { ab = true; break; }
                    if (guard > SPIN_LIMIT) {
                        __hip_atomic_store(abortp, 1u, __ATOMIC_RELAXED, __HIP_MEMORY_SCOPE_AGENT);
                        ab = true; break;
                    }
                }
            }
            if (lane == 0) {
                int vv = 1;
                if (!ab && (t % 10) == 2)
                    vv = (int)__hip_atomic_load(&viol[(t - 2) / 10],
                                                __ATOMIC_RELAXED, __HIP_MEMORY_SCOPE_AGENT);
                *(volatile int*)&s_viol_val = vv;     // DS ops in-order: viol before go
                *(volatile int*)&s_go = ab ? GO_ABORT : t;
            }
        } else {
            volatile int* gp = (volatile int*)&s_go;
            int guard = 0;
            while (*gp < t) {
                __builtin_amdgcn_s_sleep(1);
                if (++guard > LDS_SPIN_LIMIT) break;   // fail loud, never hang
            }
        }
        const int go = *(volatile int*)&s_go;
        if (go == GO_ABORT || go < t) { aborted = true; f_final = fl; break; }

        // convergence decision: viol for check k=t-2 (computed in pass t-1) is
        // quiescent once pass-t counts hit target (ORs are release-ordered
        // before each producer's count ADD). Uniform across blocks.
        if ((t % 10) == 2 && *(volatile int*)&s_viol_val == 0) {
            f_final = p ? fA : fB;       // f_{t-1}, staged last pass
            break;
        }

        // ---- stage f_t: acquire fence, then plain coalesced loads (data quiescent)
        __threadfence();
        ((float4*)fl)[tid] = ((const float4*)fsrc)[tid];
        __syncthreads();

        if (t == MAX_ITER) { f_final = fl; break; }   // f_1000, just staged

        // ---- compute f_{t+1}[row] = 0.5*(f_t[row] - eps*LSE_j((f_t[j]-M[row][j])/eps))
        const float4* ml4 = (const float4*)m_lds[wave];
        const float4* fl4 = (const float4*)fl;
        float x[32];
        float mloc = -INFINITY;
        #pragma unroll
        for (int k = 0; k < 8; ++k) {
            const int idx = (k << 6) + lane;
            const float4 mv = ml4[idx];
            const float4 f4 = fl4[idx];
            const float x0 = (f4.x - mv.x) * inv_eps;
            const float x1 = (f4.y - mv.y) * inv_eps;
            const float x2 = (f4.z - mv.z) * inv_eps;
            const float x3 = (f4.w - mv.w) * inv_eps;
            x[4*k+0] = x0; x[4*k+1] = x1; x[4*k+2] = x2; x[4*k+3] = x3;
            mloc = fmaxf(mloc, fmaxf(fmaxf(x0, x1), fmaxf(x2, x3)));
        }
        float mw = mloc;
        #pragma unroll
        for (int off = 32; off; off >>= 1)
            mw = fmaxf(mw, __shfl_down(mw, off));
        mw = __shfl(mw, 0);
        float s = 0.0f;
        #pragma unroll
        for (int k = 0; k < 32; ++k) s += expf(x[k] - mw);
        #pragma unroll
        for (int off = 32; off; off >>= 1)
            s += __shfl_down(s, off);

        if (lane == 0) {
            const float L  = mw + logf(s);
            const float fi = fl[row];
            const float fn = 0.5f * (fi - eps * L);
            float* fdst = p ? fbuf0 : fbuf1;
            __hip_atomic_store(&fdst[row], fn, __ATOMIC_RELAXED, __HIP_MEMORY_SCOPE_AGENT);
            if ((t % 10) == 1) {          // reference check at k=t-1 on f_t
                const float rs = expf(fi * inv_eps + L);
                if (!(fabsf(rs - 1.0f) < TOLF))
                    __hip_atomic_fetch_or(&viol[(t - 1) / 10], 1u,
                                          __ATOMIC_RELAXED, __HIP_MEMORY_SCOPE_AGENT);
            }
            // release: f store (and viol OR) visible at IF before this count bump
            __hip_atomic_fetch_add(&cw[(1 - p) * 1024 + (row >> 5) * CWSTRIDE], 1u,
                                   __ATOMIC_RELEASE, __HIP_MEMORY_SCOPE_AGENT);
        }
        // no block barrier here: next pass's poll IS the synchronization
    }

    // ---- loss epilogue: sum_ij g*(log g - logQ - 1) + exp(logQ); logQ=(f_i+f_j-M)/eps
    __syncthreads();
    const float4* Grow = (const float4*)(Gg + (size_t)row * NN);
    const float4* ml4  = (const float4*)m_lds[wave];
    const float4* fl4  = (const float4*)f_final;
    const float   fi   = f_final[row];
    double lsum = 0.0;
    #pragma unroll
    for (int k = 0; k < 8; ++k) {
        const int idx = (k << 6) + lane;
        const float4 mv = ml4[idx];
        const float4 gv = Grow[idx];
        const float4 f4 = fl4[idx];
        {
            const float lq = (fi + f4.x - mv.x) * inv_eps;
            lsum += (double)(gv.x * (logf(gv.x) - lq - 1.0f) + expf(lq));
        }
        {
            const float lq = (fi + f4.y - mv.y) * inv_eps;
            lsum += (double)(gv.y * (logf(gv.y) - lq - 1.0f) + expf(lq));
        }
        {
            const float lq = (fi + f4.z - mv.z) * inv_eps;
            lsum += (double)(gv.z * (logf(gv.z) - lq - 1.0f) + expf(lq));
        }
        {
            const float lq = (fi + f4.w - mv.w) * inv_eps;
            lsum += (double)(gv.w * (logf(gv.w) - lq - 1.0f) + expf(lq));
        }
    }
    #pragma unroll
    for (int off = 32; off; off >>= 1)
        lsum += __shfl_down(lsum, off);

    if (lane == 0) s_part[wave] = lsum;
    __syncthreads();
    if (tid == 0) {
        double b = 0.0;
        #pragma unroll
        for (int w = 0; w < WPB; ++w) b += s_part[w];
        atomicAdd(acc, b);
        __threadfence();
        const unsigned int prev = __hip_atomic_fetch_add(done_cnt, 1u,
                                                         __ATOMIC_RELAXED, __HIP_MEMORY_SCOPE_AGENT);
        if (prev == NBLK - 1) {   // last block finalizes
            __threadfence();
            const double total = __hip_atomic_load(acc, __ATOMIC_RELAXED,
                                                   __HIP_MEMORY_SCOPE_AGENT);
            out[0] = (float)(250.0 * total);
        }
    }
}

extern "C" void kernel_launch(void* const* d_in, const int* in_sizes, int n_in,
                              void* d_out, int out_size, void* d_ws, size_t ws_size,
                              hipStream_t stream)
{
    const float* Mm    = (const float*)d_in[0];
    const float* Gg    = (const float*)d_in[1];
    const int*   eps_p = (const int*)d_in[2];
    float* out = (float*)d_out;
    unsigned int* ws32 = (unsigned int*)d_ws;

    void* args[] = { (void*)&Mm, (void*)&Gg, (void*)&eps_p, (void*)&out, (void*)&ws32 };
    hipLaunchCooperativeKernel((void*)xgr_sinkhorn, dim3(NBLK), dim3(TPB),
                               args, 0, stream);
}

// Round 6
// 298.536 us; speedup vs baseline: 4.3360x; 4.3360x over previous
//
#include <hip/hip_runtime.h>
#include <hip/hip_cooperative_groups.h>
#include <math.h>

namespace cg = cooperative_groups;

#define NN 2048
#define MAX_ITER 1000
#define TOLF 1e-6f
#define TPB 512
#define NBLK 256
#define WPB 8                  // waves per block; NBLK*WPB == NN (one wave per row)
#define SPIN_LIMIT (1 << 14)   // VMEM poll rounds before abort
#define LDS_SPIN_LIMIT (1 << 18)
#define FLAG_ABORT 0x7f000000

// pair word: [63:33]=tag (pass number), [32]=viol bit, [31:0]=f32 bits
__device__ __forceinline__ unsigned long long pack_pair(unsigned int tag,
                                                        unsigned int viol,
                                                        float v) {
    return ((unsigned long long)((tag << 1) | viol) << 32) | (unsigned long long)__float_as_uint(v);
}

__global__ __launch_bounds__(TPB, 1)
void xgr_sinkhorn(const float* __restrict__ Mm,
                  const float* __restrict__ Gg,
                  const int* __restrict__ eps_p,
                  float* __restrict__ out,
                  unsigned long long* __restrict__ ws64)
{
    __shared__ float  m_lds[WPB][NN];   // 64 KB: this block's 8 M rows
    __shared__ float  fA[NN], fB[NN];   // f_t staging, double-buffered by parity
    __shared__ int    sflag[2][WPB];    // per-parity, per-slice validated-tag flags
    __shared__ double s_part[WPB];

    // workspace: two tagged f buffers (by pass parity), then accumulator/counters.
    // NO fences anywhere in the loop: all cross-XCD sync rides relaxed atomics
    // on fused value+tag words (single-word atomicity is the only requirement).
    unsigned long long* gb0 = ws64;         // holds f_t for even t
    unsigned long long* gb1 = ws64 + NN;    // odd t
    double*       acc      = (double*)(ws64 + 2 * NN);
    unsigned int* done_cnt = (unsigned int*)(ws64 + 2 * NN + 1);
    unsigned int* abortp   = done_cnt + 1;

    const int tid  = threadIdx.x;
    const int lane = tid & 63;
    const int wave = tid >> 6;
    const int row  = blockIdx.x * WPB + wave;
    const int gtid = blockIdx.x * TPB + tid;

    // init: each block owns its 8 rows' slots in both buffers
    if (tid < WPB) {
        const int r = blockIdx.x * WPB + tid;
        gb0[r] = 0ULL;                        // f_0 = 0.0f, tag 0, viol 0
        gb1[r] = 0xFFFFFFFF00000000ULL;       // invalid tag
    }
    if (gtid == 0) { *acc = 0.0; *done_cnt = 0u; *abortp = 0u; }
    if (tid < 2 * WPB) ((int*)sflag)[tid] = -1;

    const int ebits = *eps_p;
    const float eps = (ebits >= 1 && ebits <= (1 << 20)) ? (float)ebits
                                                         : __int_as_float(ebits);
    const float inv_eps = 1.0f / eps;

    // stage this block's 8 M rows into LDS (once)
    {
        const float4* Mrow = (const float4*)(Mm + (size_t)row * NN);
        float4* ml4 = (float4*)m_lds[wave];
        #pragma unroll
        for (int k = 0; k < 8; ++k) {
            const int idx = (k << 6) + lane;
            ml4[idx] = Mrow[idx];
        }
    }

    cg::this_grid().sync();   // init visible device-wide; tag protocol takes over

    float* f_final = nullptr;
    bool   aborted = false;

    for (int t = 0; ; ++t) {
        const int p = t & 1;
        float* fl = p ? fB : fA;
        unsigned long long* gb  = p ? gb1 : gb0;
        unsigned long long* gbn = p ? gb0 : gb1;

        // ---- validate + stage OWN slice: wave w owns rows [256w, 256w+256).
        // lane l's 4 words are columns 256w+4l..+3 (exactly what lane l consumes
        // for chunk w). Value+tag fused per word -> no fences needed.
        {
            const unsigned int want = (unsigned int)t;
            unsigned long long* gw = gb + (wave << 8) + (lane << 2);
            unsigned long long pw0 = 0, pw1 = 0, pw2 = 0, pw3 = 0;
            bool ok0 = false, ok1 = false, ok2 = false, ok3 = false;
            int vio = 0, guard = 0;
            for (;;) {
                if (!ok0) { unsigned long long q = __hip_atomic_load(gw + 0, __ATOMIC_RELAXED, __HIP_MEMORY_SCOPE_AGENT);
                            if ((unsigned int)(q >> 33) == want) { ok0 = true; pw0 = q; vio |= (int)((q >> 32) & 1ULL); } }
                if (!ok1) { unsigned long long q = __hip_atomic_load(gw + 1, __ATOMIC_RELAXED, __HIP_MEMORY_SCOPE_AGENT);
                            if ((unsigned int)(q >> 33) == want) { ok1 = true; pw1 = q; vio |= (int)((q >> 32) & 1ULL); } }
                if (!ok2) { unsigned long long q = __hip_atomic_load(gw + 2, __ATOMIC_RELAXED, __HIP_MEMORY_SCOPE_AGENT);
                            if ((unsigned int)(q >> 33) == want) { ok2 = true; pw2 = q; vio |= (int)((q >> 32) & 1ULL); } }
                if (!ok3) { unsigned long long q = __hip_atomic_load(gw + 3, __ATOMIC_RELAXED, __HIP_MEMORY_SCOPE_AGENT);
                            if ((unsigned int)(q >> 33) == want) { ok3 = true; pw3 = q; vio |= (int)((q >> 32) & 1ULL); } }
                if (__all(ok0 && ok1 && ok2 && ok3)) break;
                if ((++guard & 63) == 0) {
                    int ab = 0;
                    if (lane == 0) ab = (int)__hip_atomic_load(abortp, __ATOMIC_RELAXED, __HIP_MEMORY_SCOPE_AGENT);
                    ab = __shfl(ab, 0);
                    if (ab || guard > SPIN_LIMIT) {
                        if (lane == 0) __hip_atomic_store(abortp, 1u, __ATOMIC_RELAXED, __HIP_MEMORY_SCOPE_AGENT);
                        aborted = true; break;
                    }
                }
            }
            float4 v;
            v.x = __uint_as_float((unsigned int)pw0);
            v.y = __uint_as_float((unsigned int)pw1);
            v.z = __uint_as_float((unsigned int)pw2);
            v.w = __uint_as_float((unsigned int)pw3);
            ((float4*)(fl + (wave << 8)))[lane] = v;
            const int wv = __any(vio != 0) ? 1 : 0;
            __threadfence_block();   // ds writes visible before flag (block scope: cheap)
            if (lane == 0)
                *(volatile int*)&sflag[p][wave] = aborted ? FLAG_ABORT : ((t << 1) | wv);
        }
        if (aborted) { f_final = fl; break; }   // garbage f -> absmax screams, no hang

        // ---- chunk-pipelined compute: consume slices as they land (flag spin on LDS).
        // fmax accumulation is exactly associative/commutative -> bit-identical to
        // the round-4 two-phase version; expf sum below keeps the original order.
        float x[32];
        float mloc = -INFINITY;
        int violall = 0;
        const float4* ml4 = (const float4*)m_lds[wave];
        for (int c = 0; c < WPB; ++c) {
            volatile int* fp = &sflag[p][c];
            int v = *fp;
            int g = 0;
            while (v < (t << 1)) {
                __builtin_amdgcn_s_sleep(1);
                if ((++g & 1023) == 0) {
                    int ab = 0;
                    if (lane == 0) ab = (int)__hip_atomic_load(abortp, __ATOMIC_RELAXED, __HIP_MEMORY_SCOPE_AGENT);
                    ab = __shfl(ab, 0);
                    if (ab || g > LDS_SPIN_LIMIT) { aborted = true; break; }
                }
                v = *fp;
            }
            if (aborted || v >= FLAG_ABORT) { aborted = true; break; }
            violall |= (v & 1);
            const float4 f4 = ((const float4*)(fl + (c << 8)))[lane];
            const float4 mv = ml4[(c << 6) + lane];
            const float x0 = (f4.x - mv.x) * inv_eps;
            const float x1 = (f4.y - mv.y) * inv_eps;
            const float x2 = (f4.z - mv.z) * inv_eps;
            const float x3 = (f4.w - mv.w) * inv_eps;
            x[4*c+0] = x0; x[4*c+1] = x1; x[4*c+2] = x2; x[4*c+3] = x3;
            mloc = fmaxf(mloc, fmaxf(fmaxf(x0, x1), fmaxf(x2, x3)));
        }
        if (aborted) {
            if (lane == 0) __hip_atomic_store(abortp, 1u, __ATOMIC_RELAXED, __HIP_MEMORY_SCOPE_AGENT);
            f_final = fl; break;
        }

        // convergence: viol bits ride tag-t words (t≡2 mod 10; check at k=t-2 on
        // f_{t-1}); decision uniform across all waves/blocks (same 2048 words).
        if ((t % 10) == 2 && violall == 0) {
            f_final = p ? fA : fB;            // f_{t-1}, staged last pass
            break;
        }
        if (t == MAX_ITER) { f_final = fl; break; }   // f_1000, just staged

        float mw = mloc;
        #pragma unroll
        for (int off = 32; off; off >>= 1)
            mw = fmaxf(mw, __shfl_down(mw, off));
        mw = __shfl(mw, 0);
        float s = 0.0f;
        #pragma unroll
        for (int k = 0; k < 32; ++k) s += expf(x[k] - mw);
        #pragma unroll
        for (int off = 32; off; off >>= 1)
            s += __shfl_down(s, off);

        if (lane == 0) {
            const float L  = mw + logf(s);
            const float fi = fl[row];
            const float fn = 0.5f * (fi - eps * L);
            unsigned int viol = 0u;
            if ((t % 10) == 1) {   // reference check at k=t-1 on f_t
                const float rs = expf(fi * inv_eps + L);
                viol = (fabsf(rs - 1.0f) < TOLF) ? 0u : 1u;
            }
            __hip_atomic_store(&gbn[row], pack_pair((unsigned int)(t + 1), viol, fn),
                               __ATOMIC_RELAXED, __HIP_MEMORY_SCOPE_AGENT);
        }
        // no barrier: next pass's validation IS the synchronization
    }

    // ---- loss epilogue: sum_ij g*(log g - logQ - 1) + exp(logQ); logQ=(f_i+f_j-M)/eps
    __syncthreads();
    const float4* Grow = (const float4*)(Gg + (size_t)row * NN);
    const float4* ml4  = (const float4*)m_lds[wave];
    const float4* fl4  = (const float4*)f_final;
    const float   fi   = f_final[row];
    double lsum = 0.0;
    #pragma unroll
    for (int k = 0; k < 8; ++k) {
        const int idx = (k << 6) + lane;
        const float4 mv = ml4[idx];
        const float4 gv = Grow[idx];
        const float4 f4 = fl4[idx];
        {
            const float lq = (fi + f4.x - mv.x) * inv_eps;
            lsum += (double)(gv.x * (logf(gv.x) - lq - 1.0f) + expf(lq));
        }
        {
            const float lq = (fi + f4.y - mv.y) * inv_eps;
            lsum += (double)(gv.y * (logf(gv.y) - lq - 1.0f) + expf(lq));
        }
        {
            const float lq = (fi + f4.z - mv.z) * inv_eps;
            lsum += (double)(gv.z * (logf(gv.z) - lq - 1.0f) + expf(lq));
        }
        {
            const float lq = (fi + f4.w - mv.w) * inv_eps;
            lsum += (double)(gv.w * (logf(gv.w) - lq - 1.0f) + expf(lq));
        }
    }
    #pragma unroll
    for (int off = 32; off; off >>= 1)
        lsum += __shfl_down(lsum, off);

    if (lane == 0) s_part[wave] = lsum;
    __syncthreads();
    if (tid == 0) {
        double b = 0.0;
        #pragma unroll
        for (int w = 0; w < WPB; ++w) b += s_part[w];
        atomicAdd(acc, b);
        __threadfence();   // once, outside the loop: cost amortized to zero
        const unsigned int prev = __hip_atomic_fetch_add(done_cnt, 1u,
                                                         __ATOMIC_RELAXED, __HIP_MEMORY_SCOPE_AGENT);
        if (prev == NBLK - 1) {   // last block finalizes
            __threadfence();
            const double total = __hip_atomic_load(acc, __ATOMIC_RELAXED,
                                                   __HIP_MEMORY_SCOPE_AGENT);
            out[0] = (float)(250.0 * total);
        }
    }
}

extern "C" void kernel_launch(void* const* d_in, const int* in_sizes, int n_in,
                              void* d_out, int out_size, void* d_ws, size_t ws_size,
                              hipStream_t stream)
{
    const float* Mm    = (const float*)d_in[0];
    const float* Gg    = (const float*)d_in[1];
    const int*   eps_p = (const int*)d_in[2];
    float* out = (float*)d_out;
    unsigned long long* ws64 = (unsigned long long*)d_ws;

    void* args[] = { (void*)&Mm, (void*)&Gg, (void*)&eps_p, (void*)&out, (void*)&ws64 };
    hipLaunchCooperativeKernel((void*)xgr_sinkhorn, dim3(NBLK), dim3(TPB),
                               args, 0, stream);
}